// Round 1
// baseline (377.926 us; speedup 1.0000x reference)
//
#include <hip/hip_runtime.h>
#include <hip/hip_bf16.h>
#include <stdint.h>

#define N_ROIS 6144
#define NCLS 20          // C
#define TOPK 615         // ceil(0.1 * 6144)
#define KPAD 640
#define NPAD 8192        // next pow2 >= N_ROIS
#define IOU_TH 0.25f

// ---------------------------------------------------------------------------
// K1: preds_t[c*N + n] = predict_cls[n, c+1] * predict_det[n, c+1]
// ---------------------------------------------------------------------------
__global__ void k_preds(const float* __restrict__ pc, const float* __restrict__ pd,
                        float* __restrict__ preds_t) {
    int i = blockIdx.x * blockDim.x + threadIdx.x;
    if (i >= NCLS * N_ROIS) return;
    int c = i / N_ROIS, n = i - c * N_ROIS;
    int src = n * (NCLS + 1) + (c + 1);
    preds_t[i] = pc[src] * pd[src];
}

// ---------------------------------------------------------------------------
// K2: per-class full bitonic sort of (score desc, idx asc) keys; emit top-K idx.
// key = (~score_bits << 32) | idx ; scores are >= 0 so raw bits are monotonic.
// Ascending sort of key == descending score, ascending index (stable argsort).
// ---------------------------------------------------------------------------
__global__ void k_sort(const float* __restrict__ preds_t, const int* __restrict__ labels,
                       int* __restrict__ order) {
    int c = blockIdx.x;
    if (labels[c] <= 0) return;     // uniform per block: safe early exit
    extern __shared__ unsigned long long arr[];
    int tid = threadIdx.x;
    for (int i = tid; i < NPAD; i += blockDim.x) {
        unsigned long long key;
        if (i < N_ROIS) {
            unsigned bits = __float_as_uint(preds_t[c * N_ROIS + i]);
            key = ((unsigned long long)(~bits) << 32) | (unsigned)i;
        } else {
            key = ~0ull;            // pad sorts last
        }
        arr[i] = key;
    }
    __syncthreads();
    for (unsigned k = 2; k <= NPAD; k <<= 1) {
        for (unsigned j = k >> 1; j > 0; j >>= 1) {
            for (int i = tid; i < NPAD; i += blockDim.x) {
                unsigned ixj = (unsigned)i ^ j;
                if (ixj > (unsigned)i) {
                    unsigned long long a = arr[i], b = arr[ixj];
                    bool up = ((i & k) == 0);
                    if ((a > b) == up) { arr[i] = b; arr[ixj] = a; }
                }
            }
            __syncthreads();
        }
    }
    for (int t = tid; t < TOPK; t += blockDim.x)
        order[c * KPAD + t] = (int)(arr[t] & 0xFFFFFFFFu);
}

// ---------------------------------------------------------------------------
// K3: greedy NMS per class. One 64-thread (single-wave) block per class.
// alive mask in LDS; IoU row gathered on demand (no K*K materialization).
// Matches reference exactly: pop i in order; if alive, keep and kill all
// j with iou(order[i],order[j]) >= thr (including i itself).
// ---------------------------------------------------------------------------
__global__ void k_nms(const float* __restrict__ iou, const int* __restrict__ labels,
                      const int* __restrict__ order, unsigned char* __restrict__ kept) {
    int c = blockIdx.x;
    if (labels[c] <= 0) return;
    __shared__ int order_s[TOPK];
    __shared__ unsigned char alive[TOPK];
    int tid = threadIdx.x;
    for (int j = tid; j < TOPK; j += 64) {
        order_s[j] = order[c * KPAD + j];
        alive[j] = 1;
    }
    __syncthreads();
    for (int i = 0; i < TOPK; ++i) {
        bool sel = alive[i] != 0;   // uniform LDS broadcast; single wave => lockstep
        if (sel) {
            const float* row = iou + (size_t)order_s[i] * N_ROIS;
            for (int j = tid; j < TOPK; j += 64) {
                if (alive[j] && row[order_s[j]] >= IOU_TH) alive[j] = 0;
            }
            if (tid == 0) kept[c * N_ROIS + order_s[i]] = 1;
        }
        __syncthreads();
    }
}

// ---------------------------------------------------------------------------
// K4: per-ROI label competition (== reference's sequential class overwrite with
// strict >), plus compaction of GT indices. List order is irrelevant (K5 uses an
// order-independent comparator).
// ---------------------------------------------------------------------------
__global__ void k_assign(const float* __restrict__ preds_t, const int* __restrict__ labels,
                         const unsigned char* __restrict__ kept,
                         int* __restrict__ lab, float* __restrict__ wgt,
                         int* __restrict__ gtlist, int* __restrict__ gtcount) {
    int n = blockIdx.x * blockDim.x + threadIdx.x;
    if (n >= N_ROIS) return;
    float w = -1.0f; int l = 0;
    for (int c = 0; c < NCLS; ++c) {
        if (labels[c] > 0 && kept[c * N_ROIS + n]) {
            float p = preds_t[c * N_ROIS + n];
            if (p > w) { w = p; l = c + 1; }
        }
    }
    lab[n] = l; wgt[n] = w;
    if (l > 0) {
        int pos = atomicAdd(gtcount, 1);
        gtlist[pos] = n;
    }
}

// ---------------------------------------------------------------------------
// K5: per-row max over GT columns. iou_map is symmetric, so read GT *rows*
// (iou[j*N + n]) -> coalesced across n. Tie-break: max v, then min j (==
// jnp.argmax first occurrence). J==0 path reproduces reference exactly
// (max_v=-1, max_i=0 -> bg onehot, loss_weight = gt_weights[0] = -1).
// ---------------------------------------------------------------------------
__global__ void k_final(const float* __restrict__ iou, const int* __restrict__ lab,
                        const float* __restrict__ wgt, const int* __restrict__ gtlist,
                        const int* __restrict__ gtcount, float* __restrict__ out) {
    int n = blockIdx.x * blockDim.x + threadIdx.x;
    if (n >= N_ROIS) return;
    int J = *gtcount;
    float maxv; int maxi;
    if (J == 0) { maxv = -1.0f; maxi = 0; }
    else {
        maxv = -2.0f; maxi = N_ROIS;
        for (int t = 0; t < J; ++t) {
            int j = gtlist[t];
            float v = iou[(size_t)j * N_ROIS + n];
            if (v > maxv || (v == maxv && j < maxi)) { maxv = v; maxi = j; }
        }
    }
    float lw = wgt[maxi];
    int pl = lab[maxi];
    bool ignore = (maxv == 0.0f);
    bool bg = (maxv < IOU_TH) && !ignore;
    float row[NCLS + 1];
    #pragma unroll
    for (int k = 0; k <= NCLS; ++k) row[k] = 0.0f;
    if (ignore) { lw = 0.0f; }
    else if (bg) { row[0] = 1.0f; }
    else if (pl > 0) { row[pl] = 1.0f; }
    // outputs: pseudo_labels (N x 21), pseudo_iou_label (N), loss_weights (N)
    #pragma unroll
    for (int k = 0; k <= NCLS; ++k) out[(size_t)n * (NCLS + 1) + k] = row[k];
    out[(size_t)N_ROIS * (NCLS + 1) + n] = maxv;
    out[(size_t)N_ROIS * (NCLS + 1) + N_ROIS + n] = lw;
}

// ---------------------------------------------------------------------------
extern "C" void kernel_launch(void* const* d_in, const int* in_sizes, int n_in,
                              void* d_out, int out_size, void* d_ws, size_t ws_size,
                              hipStream_t stream) {
    const float* pc     = (const float*)d_in[0];   // predict_cls (N, C+1)
    const float* pd     = (const float*)d_in[1];   // predict_det (N, C+1)
    // d_in[2] = rois: unused by the reference result
    const int*   labels = (const int*)d_in[3];     // (C,)
    const float* iou    = (const float*)d_in[4];   // (N, N)
    float* out = (float*)d_out;

    char* ws = (char*)d_ws;
    size_t off = 0;
    float* preds_t = (float*)(ws + off);          off += (size_t)NCLS * N_ROIS * 4;  // 491520
    int*   order   = (int*)(ws + off);            off += (size_t)NCLS * KPAD * 4;    // 51200
    unsigned char* kept = (unsigned char*)(ws + off); off += (size_t)NCLS * N_ROIS;  // 122880
    int*   gtcount = (int*)(ws + off);            off += 4;
    int*   lab     = (int*)(ws + off);            off += (size_t)N_ROIS * 4;
    float* wgt     = (float*)(ws + off);          off += (size_t)N_ROIS * 4;
    int*   gtlist  = (int*)(ws + off);            off += (size_t)N_ROIS * 4;

    // kept + gtcount are contiguous: zero both in one async memset (ws is poisoned)
    hipMemsetAsync(kept, 0, (size_t)NCLS * N_ROIS + 4, stream);

    k_preds <<<(NCLS * N_ROIS + 255) / 256, 256, 0, stream>>>(pc, pd, preds_t);
    k_sort  <<<NCLS, 1024, NPAD * sizeof(unsigned long long), stream>>>(preds_t, labels, order);
    k_nms   <<<NCLS, 64, 0, stream>>>(iou, labels, order, kept);
    k_assign<<<(N_ROIS + 255) / 256, 256, 0, stream>>>(preds_t, labels, kept, lab, wgt, gtlist, gtcount);
    k_final <<<(N_ROIS + 255) / 256, 256, 0, stream>>>(iou, lab, wgt, gtlist, gtcount, out);
}

// Round 2
// 250.436 us; speedup vs baseline: 1.5091x; 1.5091x over previous
//
#include <hip/hip_runtime.h>
#include <hip/hip_bf16.h>
#include <stdint.h>

#define N_ROIS 6144
#define NCLS 20          // C
#define TOPK 615         // ceil(0.1 * 6144)
#define KPAD 640
#define IOU_TH 0.25f

#define BUCKETS 8192     // 2^13: score*8192 is exact (pure exponent shift), monotone
#define CAND_CAP 1024
#define NWORDS 10        // ceil(TOPK/64)

// ---------------------------------------------------------------------------
// K1: preds_t[c*N + n] = predict_cls[n, c+1] * predict_det[n, c+1]
// ---------------------------------------------------------------------------
__global__ void k_preds(const float* __restrict__ pc, const float* __restrict__ pd,
                        float* __restrict__ preds_t) {
    int i = blockIdx.x * blockDim.x + threadIdx.x;
    if (i >= NCLS * N_ROIS) return;
    int c = i / N_ROIS, n = i - c * N_ROIS;
    int src = n * (NCLS + 1) + (c + 1);
    preds_t[i] = pc[src] * pd[src];
}

// ---------------------------------------------------------------------------
// K2: per-class exact top-K via bucket-select + small bitonic sort.
//  - histogram of (int)(score*8192) : monotone bucketing, exact fp scaling
//  - suffix scan to find threshold bucket where cumulative count >= K
//  - compact candidates (>= threshold bucket), |cand| ~ K + bucket width
//  - bitonic sort 1024 candidates by full key (~score_bits << 32) | idx
//    == stable argsort by (-score, idx). Emit top-K indices in order.
// ---------------------------------------------------------------------------
__global__ __launch_bounds__(1024) void k_topk(const float* __restrict__ preds_t,
                                               const int* __restrict__ labels,
                                               int* __restrict__ order) {
    int c = blockIdx.x;
    if (labels[c] <= 0) return;              // block-uniform: safe early exit
    __shared__ int hist[BUCKETS];            // 32 KB
    __shared__ unsigned long long cand[CAND_CAP]; // 8 KB
    __shared__ int chunk[1024];              // 4 KB scan temp
    __shared__ int thresh_bucket;
    __shared__ int cand_cnt;
    int tid = threadIdx.x;

    for (int i = tid; i < BUCKETS; i += 1024) hist[i] = 0;
    if (tid == 0) cand_cnt = 0;
    __syncthreads();

    // load scores (6 per thread), histogram
    float sc[6];
    #pragma unroll
    for (int k = 0; k < 6; ++k) {
        int n = tid + k * 1024;              // 6144 = 6*1024 exactly
        float s = preds_t[c * N_ROIS + n];
        sc[k] = s;
        int b = (int)(s * (float)BUCKETS);
        b = min(max(b, 0), BUCKETS - 1);
        atomicAdd(&hist[b], 1);
    }
    __syncthreads();

    // suffix sums from the TOP bucket down. chunk t covers reversed-bucket
    // range [t*8, t*8+8), i.e. buckets BUCKETS-1-t*8 .. BUCKETS-8-t*8.
    int own = 0;
    #pragma unroll
    for (int k = 0; k < 8; ++k) own += hist[BUCKETS - 1 - (tid * 8 + k)];
    chunk[tid] = own;
    __syncthreads();
    // Hillis-Steele inclusive scan over 1024 chunks
    for (int off = 1; off < 1024; off <<= 1) {
        int v = (tid >= off) ? chunk[tid - off] : 0;
        __syncthreads();
        chunk[tid] += v;
        __syncthreads();
    }
    int inc = chunk[tid];
    int exc = inc - own;
    if (exc < TOPK && inc >= TOPK) {         // exactly one thread crosses K
        int cum = exc;
        #pragma unroll
        for (int k = 0; k < 8; ++k) {
            int rb = tid * 8 + k;
            cum += hist[BUCKETS - 1 - rb];
            if (cum >= TOPK) { thresh_bucket = BUCKETS - 1 - rb; break; }
        }
    }
    __syncthreads();
    int tb = thresh_bucket;

    // compact candidates: bucket >= tb  (count >= TOPK by construction)
    #pragma unroll
    for (int k = 0; k < 6; ++k) {
        int n = tid + k * 1024;
        float s = sc[k];
        int b = (int)(s * (float)BUCKETS);
        b = min(max(b, 0), BUCKETS - 1);
        if (b >= tb) {
            int pos = atomicAdd(&cand_cnt, 1);
            if (pos < CAND_CAP) {
                unsigned bits = __float_as_uint(s);
                cand[pos] = ((unsigned long long)(~bits) << 32) | (unsigned)n;
            }
        }
    }
    __syncthreads();
    int cc = min(cand_cnt, CAND_CAP);
    for (int i = tid; i < CAND_CAP; i += 1024)
        if (i >= cc) cand[i] = ~0ull;        // pad sorts last
    __syncthreads();

    // bitonic sort CAND_CAP=1024 elements ascending (desc score, asc idx)
    for (unsigned k2 = 2; k2 <= CAND_CAP; k2 <<= 1) {
        for (unsigned j = k2 >> 1; j > 0; j >>= 1) {
            unsigned i = (unsigned)tid;
            unsigned ixj = i ^ j;
            if (ixj > i) {
                unsigned long long a = cand[i], b = cand[ixj];
                bool up = ((i & k2) == 0);
                if ((a > b) == up) { cand[i] = b; cand[ixj] = a; }
            }
            __syncthreads();
        }
    }
    if (tid < TOPK) order[c * KPAD + tid] = (int)(cand[tid] & 0xFFFFFFFFu);
}

// ---------------------------------------------------------------------------
// K3: greedy NMS, single wave per class, alive as a 615-bit mask.
// Jump directly to the next live candidate (find-first-set) so the loop
// runs ~#kept (~5-8) times instead of 615.
// ---------------------------------------------------------------------------
__global__ __launch_bounds__(64) void k_nms(const float* __restrict__ iou,
                                            const int* __restrict__ labels,
                                            const int* __restrict__ order,
                                            unsigned char* __restrict__ kept) {
    int c = blockIdx.x;
    if (labels[c] <= 0) return;
    __shared__ int order_s[TOPK];
    __shared__ unsigned long long alive[NWORDS];
    int lane = threadIdx.x;
    for (int j = lane; j < TOPK; j += 64) order_s[j] = order[c * KPAD + j];
    if (lane < NWORDS) {
        unsigned long long m = ~0ull;
        if (lane == NWORDS - 1) m = (1ull << (TOPK - 64 * (NWORDS - 1))) - 1; // 39 bits
        alive[lane] = m;
    }
    __syncthreads();

    int i = 0;
    while (true) {
        // find next alive index >= i (uniform LDS broadcast reads)
        int next = -1;
        for (int w = i >> 6; w < NWORDS; ++w) {
            unsigned long long m = alive[w];
            if (w == (i >> 6)) m &= (~0ull) << (i & 63);
            if (m) { next = w * 64 + __builtin_ctzll(m); break; }
        }
        if (next < 0) break;
        i = next;
        int bi = order_s[i];
        const float* row = iou + (size_t)bi * N_ROIS;
        #pragma unroll
        for (int k = 0; k < NWORDS; ++k) {
            unsigned long long w = alive[k];
            int j = k * 64 + lane;
            bool sup = false;
            if ((w >> lane) & 1ull)                 // alive => j < TOPK
                sup = row[order_s[j]] >= IOU_TH;    // row[bi]==1.0 kills i itself
            unsigned long long bal = __ballot(sup);
            if (lane == 0) alive[k] = w & ~bal;
        }
        if (lane == 0) kept[c * N_ROIS + bi] = 1;
        __syncthreads();                            // single wave: cheap, for LDS visibility
    }
}

// ---------------------------------------------------------------------------
// K4: per-ROI label competition (== reference sequential overwrite, strict >),
// plus GT index compaction (order-independent downstream).
// ---------------------------------------------------------------------------
__global__ void k_assign(const float* __restrict__ preds_t, const int* __restrict__ labels,
                         const unsigned char* __restrict__ kept,
                         int* __restrict__ lab, float* __restrict__ wgt,
                         int* __restrict__ gtlist, int* __restrict__ gtcount) {
    int n = blockIdx.x * blockDim.x + threadIdx.x;
    if (n >= N_ROIS) return;
    float w = -1.0f; int l = 0;
    for (int c = 0; c < NCLS; ++c) {
        if (labels[c] > 0 && kept[c * N_ROIS + n]) {
            float p = preds_t[c * N_ROIS + n];
            if (p > w) { w = p; l = c + 1; }
        }
    }
    lab[n] = l; wgt[n] = w;
    if (l > 0) {
        int pos = atomicAdd(gtcount, 1);
        gtlist[pos] = n;
    }
}

// ---------------------------------------------------------------------------
// K5: per-row max over GT columns via symmetric rows (coalesced across n).
// Tie-break (max v, min j) == jnp.argmax first occurrence.
// ---------------------------------------------------------------------------
__global__ void k_final(const float* __restrict__ iou, const int* __restrict__ lab,
                        const float* __restrict__ wgt, const int* __restrict__ gtlist,
                        const int* __restrict__ gtcount, float* __restrict__ out) {
    int n = blockIdx.x * blockDim.x + threadIdx.x;
    if (n >= N_ROIS) return;
    int J = *gtcount;
    float maxv; int maxi;
    if (J == 0) { maxv = -1.0f; maxi = 0; }
    else {
        maxv = -2.0f; maxi = N_ROIS;
        for (int t = 0; t < J; ++t) {
            int j = gtlist[t];
            float v = iou[(size_t)j * N_ROIS + n];
            if (v > maxv || (v == maxv && j < maxi)) { maxv = v; maxi = j; }
        }
    }
    float lw = wgt[maxi];
    int pl = lab[maxi];
    bool ignore = (maxv == 0.0f);
    bool bg = (maxv < IOU_TH) && !ignore;
    float row[NCLS + 1];
    #pragma unroll
    for (int k = 0; k <= NCLS; ++k) row[k] = 0.0f;
    if (ignore) { lw = 0.0f; }
    else if (bg) { row[0] = 1.0f; }
    else if (pl > 0) { row[pl] = 1.0f; }
    #pragma unroll
    for (int k = 0; k <= NCLS; ++k) out[(size_t)n * (NCLS + 1) + k] = row[k];
    out[(size_t)N_ROIS * (NCLS + 1) + n] = maxv;
    out[(size_t)N_ROIS * (NCLS + 1) + N_ROIS + n] = lw;
}

// ---------------------------------------------------------------------------
extern "C" void kernel_launch(void* const* d_in, const int* in_sizes, int n_in,
                              void* d_out, int out_size, void* d_ws, size_t ws_size,
                              hipStream_t stream) {
    const float* pc     = (const float*)d_in[0];   // predict_cls (N, C+1)
    const float* pd     = (const float*)d_in[1];   // predict_det (N, C+1)
    // d_in[2] = rois: unused by the reference result
    const int*   labels = (const int*)d_in[3];     // (C,)
    const float* iou    = (const float*)d_in[4];   // (N, N)
    float* out = (float*)d_out;

    char* ws = (char*)d_ws;
    size_t off = 0;
    float* preds_t = (float*)(ws + off);          off += (size_t)NCLS * N_ROIS * 4;
    int*   order   = (int*)(ws + off);            off += (size_t)NCLS * KPAD * 4;
    unsigned char* kept = (unsigned char*)(ws + off); off += (size_t)NCLS * N_ROIS;
    int*   gtcount = (int*)(ws + off);            off += 4;
    int*   lab     = (int*)(ws + off);            off += (size_t)N_ROIS * 4;
    float* wgt     = (float*)(ws + off);          off += (size_t)N_ROIS * 4;
    int*   gtlist  = (int*)(ws + off);            off += (size_t)N_ROIS * 4;

    // kept + gtcount are contiguous: zero both in one async memset
    hipMemsetAsync(kept, 0, (size_t)NCLS * N_ROIS + 4, stream);

    k_preds <<<(NCLS * N_ROIS + 255) / 256, 256, 0, stream>>>(pc, pd, preds_t);
    k_topk  <<<NCLS, 1024, 0, stream>>>(preds_t, labels, order);
    k_nms   <<<NCLS, 64, 0, stream>>>(iou, labels, order, kept);
    k_assign<<<(N_ROIS + 255) / 256, 256, 0, stream>>>(preds_t, labels, kept, lab, wgt, gtlist, gtcount);
    k_final <<<(N_ROIS + 255) / 256, 256, 0, stream>>>(iou, lab, wgt, gtlist, gtcount, out);
}